// Round 1
// baseline (284.861 us; speedup 1.0000x reference)
//
#include <hip/hip_runtime.h>

// DirectNormLoss: B=16384 rows, D=2048 features, 1000 classes.
// loss = mean_i [ 1 - <s_i, c_i> / (||c_i|| * max(||s_i||, ||t_i||)) ]
//
// R5: Top-5 rocprof dispatches are all 512MiB harness poison fills (~78us
// each, 2/iter ~= 156us fixed); main kernel ~110us vs ~44us traffic floor.
// R3 evidence: fetch (142-187MB) << logical (268MB) yet time pinned at
// 110us -> not HBM-BW-bound, not latency-bound (cycle math ~3us). Theory:
// 3-way stream interleave (s0,t0,c0,s1,t1,c1,...) thrashes DRAM pages /
// request queues with alternating 1KiB bursts. This round:
//  - per-stream BURSTS: 8x dwordx4 s, then t, then c (8KiB contiguous per
//    stream per wave, in-order completion lets compute overlap tail loads)
//  - drop nontemporal (restore the cross-iteration LLC retention R3 saw)
//  - __launch_bounds__(256,4): pin 4 waves/SIMD (VGPR est ~120 < 128 cap)

#define NROWS  16384
#define DDIM   2048
#define BLK    256
#define WPB    (BLK / 64)          // 4 waves per block
#define GRID   (NROWS / WPB)       // 4096 blocks -> 16384 waves, 1 row each

typedef float v4f __attribute__((ext_vector_type(4)));

__device__ __forceinline__ float dot4(const v4f a, const v4f b) {
    return a.x*b.x + a.y*b.y + a.z*b.z + a.w*b.w;
}

__global__ __launch_bounds__(BLK, 4) void dnl_main_kernel(
    const float* __restrict__ s_emb,
    const float* __restrict__ t_emb,
    const float* __restrict__ T_EMB,
    const int*   __restrict__ labels,
    float*       __restrict__ partial)   // [NROWS]
{
    const int tid  = threadIdx.x;
    const int lane = tid & 63;
    const int row  = blockIdx.x * WPB + (tid >> 6);   // wave-uniform

    const int label = labels[row];                    // issued first

    const v4f* s4 = (const v4f*)(s_emb + (size_t)row   * DDIM);
    const v4f* t4 = (const v4f*)(t_emb + (size_t)row   * DDIM);
    const v4f* c4 = (const v4f*)(T_EMB + (size_t)label * DDIM);

    // 512 float4 per row; 64 lanes -> 8 per lane per stream.
    // Issue each stream as one contiguous 8KiB burst (ascending addresses)
    // instead of interleaving the three streams load-by-load.
    v4f sr[8], tr[8], cr[8];
    #pragma unroll
    for (int j = 0; j < 8; ++j) sr[j] = s4[lane + j * 64];
    #pragma unroll
    for (int j = 0; j < 8; ++j) tr[j] = t4[lane + j * 64];
    #pragma unroll
    for (int j = 0; j < 8; ++j) cr[j] = c4[lane + j * 64];

    // In-order vmcnt completion: ss can start once the s burst lands,
    // overlapping the t/c bursts still in flight.
    float ss = 0.f, tt = 0.f, sc = 0.f, cc = 0.f;
    #pragma unroll
    for (int j = 0; j < 8; ++j) ss += dot4(sr[j], sr[j]);
    #pragma unroll
    for (int j = 0; j < 8; ++j) tt += dot4(tr[j], tr[j]);
    #pragma unroll
    for (int j = 0; j < 8; ++j) { sc += dot4(sr[j], cr[j]); cc += dot4(cr[j], cr[j]); }

    // wave-64 xor butterfly: all lanes end with full row sums
    #pragma unroll
    for (int off = 32; off > 0; off >>= 1) {
        ss += __shfl_xor(ss, off, 64);
        tt += __shfl_xor(tt, off, 64);
        sc += __shfl_xor(sc, off, 64);
        cc += __shfl_xor(cc, off, 64);
    }

    if (lane == 0) {
        const float max_norm = fmaxf(sqrtf(ss), sqrtf(tt));
        partial[row] = 1.0f - sc / (sqrtf(cc) * max_norm);
    }
}

__global__ __launch_bounds__(BLK) void dnl_reduce_kernel(
    const float* __restrict__ partial,
    float*       __restrict__ out)
{
    const int tid = threadIdx.x;
    const float4* p4 = (const float4*)partial;
    // NROWS/4 = 4096 float4; 256 threads -> 16 each, coalesced.
    float sum = 0.f;
    #pragma unroll
    for (int j = 0; j < 16; ++j) {
        const float4 v = p4[tid + j * BLK];
        sum += v.x + v.y + v.z + v.w;
    }

    #pragma unroll
    for (int off = 32; off > 0; off >>= 1)
        sum += __shfl_xor(sum, off, 64);

    __shared__ float red[4];
    if ((tid & 63) == 0) red[tid >> 6] = sum;
    __syncthreads();
    if (tid == 0)
        out[0] = (red[0] + red[1] + red[2] + red[3]) * (1.0f / (float)NROWS);
}

// Atomic fallback (only if ws too small).
__global__ __launch_bounds__(BLK, 4) void dnl_main_atomic_kernel(
    const float* __restrict__ s_emb,
    const float* __restrict__ t_emb,
    const float* __restrict__ T_EMB,
    const int*   __restrict__ labels,
    float*       __restrict__ out)
{
    const int tid  = threadIdx.x;
    const int lane = tid & 63;
    const int row  = blockIdx.x * WPB + (tid >> 6);
    const int label = labels[row];

    const v4f* s4 = (const v4f*)(s_emb + (size_t)row   * DDIM);
    const v4f* t4 = (const v4f*)(t_emb + (size_t)row   * DDIM);
    const v4f* c4 = (const v4f*)(T_EMB + (size_t)label * DDIM);

    v4f sr[8], tr[8], cr[8];
    #pragma unroll
    for (int j = 0; j < 8; ++j) sr[j] = s4[lane + j * 64];
    #pragma unroll
    for (int j = 0; j < 8; ++j) tr[j] = t4[lane + j * 64];
    #pragma unroll
    for (int j = 0; j < 8; ++j) cr[j] = c4[lane + j * 64];

    float ss = 0.f, tt = 0.f, sc = 0.f, cc = 0.f;
    #pragma unroll
    for (int j = 0; j < 8; ++j) ss += dot4(sr[j], sr[j]);
    #pragma unroll
    for (int j = 0; j < 8; ++j) tt += dot4(tr[j], tr[j]);
    #pragma unroll
    for (int j = 0; j < 8; ++j) { sc += dot4(sr[j], cr[j]); cc += dot4(cr[j], cr[j]); }

    #pragma unroll
    for (int off = 32; off > 0; off >>= 1) {
        ss += __shfl_xor(ss, off, 64);
        tt += __shfl_xor(tt, off, 64);
        sc += __shfl_xor(sc, off, 64);
        cc += __shfl_xor(cc, off, 64);
    }
    if (lane == 0) {
        const float max_norm = fmaxf(sqrtf(ss), sqrtf(tt));
        atomicAdd(out, (1.0f - sc / (sqrtf(cc) * max_norm)) * (1.0f / (float)NROWS));
    }
}

extern "C" void kernel_launch(void* const* d_in, const int* in_sizes, int n_in,
                              void* d_out, int out_size, void* d_ws, size_t ws_size,
                              hipStream_t stream) {
    const float* s_emb  = (const float*)d_in[0];
    const float* t_emb  = (const float*)d_in[1];
    const float* T_EMB  = (const float*)d_in[2];
    const int*   labels = (const int*)d_in[3];
    float* out = (float*)d_out;

    if (ws_size >= (size_t)NROWS * sizeof(float)) {
        float* partial = (float*)d_ws;
        dnl_main_kernel<<<GRID, BLK, 0, stream>>>(s_emb, t_emb, T_EMB, labels, partial);
        dnl_reduce_kernel<<<1, BLK, 0, stream>>>(partial, out);
    } else {
        hipMemsetAsync(d_out, 0, sizeof(float), stream);
        dnl_main_atomic_kernel<<<GRID, BLK, 0, stream>>>(s_emb, t_emb, T_EMB, labels, out);
    }
}

// Round 2
// 281.797 us; speedup vs baseline: 1.0109x; 1.0109x over previous
//
#include <hip/hip_runtime.h>

// DirectNormLoss: B=16384 rows, D=2048 features, 1000 classes.
// loss = mean_i [ 1 - <s_i, c_i> / (||c_i|| * max(||s_i||, ||t_i||)) ]
//
// R6: Five structural variants all pinned at ~107-110us with NOTHING
// saturated (HBM 22%, VALU 7%, occ 60%, fetch == mandatory). R5's compiler
// schedule (VGPR=36) serialized the bursts. Theory: wave churn + per-wave
// latency exposure -- 16384 short-lived waves, 4096 WGs (2x the G11 grid
// cap). This round: persistent decomposition. 1024 blocks, 4096 waves,
// 4 rows/wave, explicit 2-deep ping-pong pipeline (issue row r+1's 24
// loads before consuming row r; all array indexing static per rule #20).
// __launch_bounds__(256,1) frees the regalloc to keep both 96-reg buffers
// live (~210 VGPR -> 2 waves/SIMD). Watch VGPR_Count: ~200 = pipeline
// real; 36 = compiler defeated it again.

#define NROWS  16384
#define DDIM   2048
#define BLK    256
#define WPB    (BLK / 64)              // 4 waves per block
#define RPW    4                       // rows per wave
#define GRID   (NROWS / (WPB * RPW))   // 1024 blocks -> 4096 waves
#define GRID_AT (NROWS / WPB)          // fallback grid (wave/row)

typedef float v4f __attribute__((ext_vector_type(4)));

__device__ __forceinline__ float dot4(const v4f a, const v4f b) {
    return a.x*b.x + a.y*b.y + a.z*b.z + a.w*b.w;
}

__global__ __launch_bounds__(BLK, 1) void dnl_main_kernel(
    const float* __restrict__ s_emb,
    const float* __restrict__ t_emb,
    const float* __restrict__ T_EMB,
    const int*   __restrict__ labels,
    float*       __restrict__ partial)   // [NROWS]
{
    const int tid  = threadIdx.x;
    const int lane = tid & 63;
    const int wave = blockIdx.x * WPB + (tid >> 6);   // wave-uniform
    const int row0 = wave * RPW;                      // 4 consecutive rows

    v4f sA[8], tA[8], cA[8];     // ping
    v4f sB[8], tB[8], cB[8];     // pong

    // Issue all 24 loads for one row (s/t/c interleaved, ascending k).
    auto issue = [&](int row, v4f* S, v4f* T, v4f* C) {
        const int label = labels[row];               // scalar (wave-uniform)
        const v4f* s4 = (const v4f*)(s_emb + (size_t)row   * DDIM);
        const v4f* t4 = (const v4f*)(t_emb + (size_t)row   * DDIM);
        const v4f* c4 = (const v4f*)(T_EMB + (size_t)label * DDIM);
        #pragma unroll
        for (int j = 0; j < 8; ++j) {
            const int k = lane + j * 64;
            S[j] = s4[k];
            T[j] = t4[k];
            C[j] = c4[k];
        }
    };

    // Reduce one row's registers and write its partial.
    auto consume = [&](int row, const v4f* S, const v4f* T, const v4f* C) {
        float ss = 0.f, tt = 0.f, sc = 0.f, cc = 0.f;
        #pragma unroll
        for (int j = 0; j < 8; ++j) {
            ss += dot4(S[j], S[j]);
            tt += dot4(T[j], T[j]);
            sc += dot4(S[j], C[j]);
            cc += dot4(C[j], C[j]);
        }
        #pragma unroll
        for (int off = 32; off > 0; off >>= 1) {
            ss += __shfl_xor(ss, off, 64);
            tt += __shfl_xor(tt, off, 64);
            sc += __shfl_xor(sc, off, 64);
            cc += __shfl_xor(cc, off, 64);
        }
        if (lane == 0) {
            const float max_norm = fmaxf(sqrtf(ss), sqrtf(tt));
            partial[row] = 1.0f - sc / (sqrtf(cc) * max_norm);
        }
    };

    // 2-deep software pipeline, fully static (no runtime-indexed arrays).
    issue  (row0 + 0, sA, tA, cA);
    issue  (row0 + 1, sB, tB, cB);
    consume(row0 + 0, sA, tA, cA);   // waits vmcnt(24): B stays in flight
    issue  (row0 + 2, sA, tA, cA);
    consume(row0 + 1, sB, tB, cB);
    issue  (row0 + 3, sB, tB, cB);
    consume(row0 + 2, sA, tA, cA);
    consume(row0 + 3, sB, tB, cB);
}

__global__ __launch_bounds__(BLK) void dnl_reduce_kernel(
    const float* __restrict__ partial,
    float*       __restrict__ out)
{
    const int tid = threadIdx.x;
    const float4* p4 = (const float4*)partial;
    // NROWS/4 = 4096 float4; 256 threads -> 16 each, coalesced.
    float sum = 0.f;
    #pragma unroll
    for (int j = 0; j < 16; ++j) {
        const float4 v = p4[tid + j * BLK];
        sum += v.x + v.y + v.z + v.w;
    }

    #pragma unroll
    for (int off = 32; off > 0; off >>= 1)
        sum += __shfl_xor(sum, off, 64);

    __shared__ float red[4];
    if ((tid & 63) == 0) red[tid >> 6] = sum;
    __syncthreads();
    if (tid == 0)
        out[0] = (red[0] + red[1] + red[2] + red[3]) * (1.0f / (float)NROWS);
}

// Atomic fallback (only if ws too small). Simple wave/row version.
__global__ __launch_bounds__(BLK, 2) void dnl_main_atomic_kernel(
    const float* __restrict__ s_emb,
    const float* __restrict__ t_emb,
    const float* __restrict__ T_EMB,
    const int*   __restrict__ labels,
    float*       __restrict__ out)
{
    const int tid  = threadIdx.x;
    const int lane = tid & 63;
    const int row  = blockIdx.x * WPB + (tid >> 6);
    const int label = labels[row];

    const v4f* s4 = (const v4f*)(s_emb + (size_t)row   * DDIM);
    const v4f* t4 = (const v4f*)(t_emb + (size_t)row   * DDIM);
    const v4f* c4 = (const v4f*)(T_EMB + (size_t)label * DDIM);

    float ss = 0.f, tt = 0.f, sc = 0.f, cc = 0.f;
    #pragma unroll
    for (int j = 0; j < 8; ++j) {
        const int k = lane + j * 64;
        const v4f s = s4[k];
        const v4f t = t4[k];
        const v4f c = c4[k];
        ss += dot4(s, s);
        tt += dot4(t, t);
        sc += dot4(s, c);
        cc += dot4(c, c);
    }
    #pragma unroll
    for (int off = 32; off > 0; off >>= 1) {
        ss += __shfl_xor(ss, off, 64);
        tt += __shfl_xor(tt, off, 64);
        sc += __shfl_xor(sc, off, 64);
        cc += __shfl_xor(cc, off, 64);
    }
    if (lane == 0) {
        const float max_norm = fmaxf(sqrtf(ss), sqrtf(tt));
        atomicAdd(out, (1.0f - sc / (sqrtf(cc) * max_norm)) * (1.0f / (float)NROWS));
    }
}

extern "C" void kernel_launch(void* const* d_in, const int* in_sizes, int n_in,
                              void* d_out, int out_size, void* d_ws, size_t ws_size,
                              hipStream_t stream) {
    const float* s_emb  = (const float*)d_in[0];
    const float* t_emb  = (const float*)d_in[1];
    const float* T_EMB  = (const float*)d_in[2];
    const int*   labels = (const int*)d_in[3];
    float* out = (float*)d_out;

    if (ws_size >= (size_t)NROWS * sizeof(float)) {
        float* partial = (float*)d_ws;
        dnl_main_kernel<<<GRID, BLK, 0, stream>>>(s_emb, t_emb, T_EMB, labels, partial);
        dnl_reduce_kernel<<<1, BLK, 0, stream>>>(partial, out);
    } else {
        hipMemsetAsync(d_out, 0, sizeof(float), stream);
        dnl_main_atomic_kernel<<<GRID_AT, BLK, 0, stream>>>(s_emb, t_emb, T_EMB, labels, out);
    }
}